// Round 1
// baseline (171.339 us; speedup 1.0000x reference)
//
#include <hip/hip_runtime.h>
#include <math.h>

#define B_  4096
#define F_  256
#define T_  128
#define D_  6
#define U_  16
#define NB_ 64
#define N_  (T_ * D_)   // 768

// ---------------------------------------------------------------------------
// K1: sparsemax over last dim (6) of (F*T, 6) rows
// ---------------------------------------------------------------------------
__global__ __launch_bounds__(256) void sparsemax6(const float* __restrict__ z,
                                                  float* __restrict__ out, int rows) {
    int r = blockIdx.x * 256 + threadIdx.x;
    if (r >= rows) return;
    const float* zp = z + (size_t)r * 6;
    float v0 = zp[0], v1 = zp[1], v2 = zp[2], v3 = zp[3], v4 = zp[4], v5 = zp[5];
    float s0 = v0, s1 = v1, s2 = v2, s3 = v3, s4 = v4, s5 = v5;
    // descending sort: odd-even transposition, 6 rounds (provably sorts n=6)
#define CE(a, b) { float hi_ = fmaxf(a, b), lo_ = fminf(a, b); a = hi_; b = lo_; }
    CE(s0, s1) CE(s2, s3) CE(s4, s5)
    CE(s1, s2) CE(s3, s4)
    CE(s0, s1) CE(s2, s3) CE(s4, s5)
    CE(s1, s2) CE(s3, s4)
    CE(s0, s1) CE(s2, s3) CE(s4, s5)
    CE(s1, s2) CE(s3, s4)
#undef CE
    // support is a prefix for sorted-descending input
    float cum = 0.f, num = 0.f, kz = 1.f;
    cum += s0; num = cum; kz = 1.f;                    // k=1: 1 + z0 > z0 always
    cum += s1; if (1.f + 2.f * s1 > cum) { num = cum; kz = 2.f; }
    cum += s2; if (1.f + 3.f * s2 > cum) { num = cum; kz = 3.f; }
    cum += s3; if (1.f + 4.f * s3 > cum) { num = cum; kz = 4.f; }
    cum += s4; if (1.f + 5.f * s4 > cum) { num = cum; kz = 5.f; }
    cum += s5; if (1.f + 6.f * s5 > cum) { num = cum; kz = 6.f; }
    float tau = (num - 1.f) / kz;
    float* op = out + (size_t)r * 6;
    op[0] = fmaxf(v0 - tau, 0.f); op[1] = fmaxf(v1 - tau, 0.f);
    op[2] = fmaxf(v2 - tau, 0.f); op[3] = fmaxf(v3 - tau, 0.f);
    op[4] = fmaxf(v4 - tau, 0.f); op[5] = fmaxf(v5 - tau, 0.f);
}

// ---------------------------------------------------------------------------
// K2: fv(4096x768) = x(4096x256) @ sel(256x768), fp32 register-tiled SGEMM
// BM=128, BN=64, BK=16; 256 threads; per-thread 8x4 outputs
// ---------------------------------------------------------------------------
#define BM 128
#define BN 64
#define BK 16

__global__ __launch_bounds__(256) void sgemm_fv(const float* __restrict__ A,  // (4096,256)
                                                const float* __restrict__ Bm, // (256,768)
                                                float* __restrict__ C) {      // (4096,768)
    __shared__ __align__(16) float As[BK][BM + 4];  // transposed [k][m], pad
    __shared__ __align__(16) float Bs[BK][BN];
    int tid = threadIdx.x;
    int m0 = blockIdx.y * BM;
    int n0 = blockIdx.x * BN;
    int tx = tid & 15;          // n-group (4 cols)
    int ty = tid >> 4;          // m-group (8 rows)
    float acc[8][4];
#pragma unroll
    for (int i = 0; i < 8; i++)
#pragma unroll
        for (int j = 0; j < 4; j++) acc[i][j] = 0.f;

    int b_row = tid >> 4;             // 0..15
    int b_col = (tid & 15) * 4;       // 0..60

    for (int kt = 0; kt < F_; kt += BK) {
        // A tile: 128x16 = 512 float4; 2 per thread, store transposed
#pragma unroll
        for (int p = 0; p < 2; p++) {
            int idx = tid + p * 256;
            int ar = idx >> 2;
            int ac = (idx & 3) * 4;
            float4 a = *(const float4*)(A + (size_t)(m0 + ar) * F_ + kt + ac);
            As[ac + 0][ar] = a.x; As[ac + 1][ar] = a.y;
            As[ac + 2][ar] = a.z; As[ac + 3][ar] = a.w;
        }
        // B tile: 16x64 = 256 float4; 1 per thread
        {
            float4 b = *(const float4*)(Bm + (size_t)(kt + b_row) * N_ + n0 + b_col);
            *(float4*)&Bs[b_row][b_col] = b;
        }
        __syncthreads();
#pragma unroll
        for (int k = 0; k < BK; k++) {
            float4 a0 = *(const float4*)&As[k][ty * 8];
            float4 a1 = *(const float4*)&As[k][ty * 8 + 4];
            float4 bb = *(const float4*)&Bs[k][tx * 4];
            float am[8] = {a0.x, a0.y, a0.z, a0.w, a1.x, a1.y, a1.z, a1.w};
            float bv[4] = {bb.x, bb.y, bb.z, bb.w};
#pragma unroll
            for (int i = 0; i < 8; i++)
#pragma unroll
                for (int j = 0; j < 4; j++)
                    acc[i][j] = fmaf(am[i], bv[j], acc[i][j]);
        }
        __syncthreads();
    }
#pragma unroll
    for (int i = 0; i < 8; i++) {
        float4 o = make_float4(acc[i][0], acc[i][1], acc[i][2], acc[i][3]);
        *(float4*)(C + (size_t)(m0 + ty * 8 + i) * N_ + n0 + tx * 4) = o;
    }
}

// ---------------------------------------------------------------------------
// K3: per (b,t) leaf weights + response contraction + sum over trees
// block: 8 b-rows x 32 t-lanes (each t-lane handles 4 trees); grid: B/8 = 512
// tid = t_local*8 + b_local  => R loads are 8-lane broadcasts (L2-resident)
// ---------------------------------------------------------------------------
__global__ __launch_bounds__(256) void leafsum(const float* __restrict__ fv,   // (4096,768)
                                               const float* __restrict__ th,   // (128,6)
                                               const float* __restrict__ lt,   // (128,6)
                                               const float* __restrict__ resp, // (128,16,64)
                                               float* __restrict__ out) {      // (4096,16)
    __shared__ float fvs[8][N_ + 1];      // +1: 769 => bank spread over b rows
    __shared__ float wacc[4][8][16];
    int tid = threadIdx.x;
    int b0 = blockIdx.x * 8;
    int b_local = tid & 7;
    int t_local = tid >> 3;               // 0..31

    // stage fv tile (coalesced)
    for (int bi = 0; bi < 8; bi++)
        for (int k = tid; k < N_; k += 256)
            fvs[bi][k] = fv[(size_t)(b0 + bi) * N_ + k];
    __syncthreads();

    float acc[16];
#pragma unroll
    for (int u = 0; u < 16; u++) acc[u] = 0.f;

    for (int j = 0; j < 4; j++) {
        int t = t_local + 32 * j;
        float bp[6], bn[6];               // bp: bit==0 value, bn: bit==1 value
#pragma unroll
        for (int d = 0; d < 6; d++) {
            float tl = (fvs[b_local][t * 6 + d] - th[t * 6 + d]) * __expf(-lt[t * 6 + d]);
            float hp = 0.5f + 0.5f * tl;  // sparsemoid(+tl)
            float hn = 0.5f - 0.5f * tl;  // sparsemoid(-tl)
            bp[d] = fminf(fmaxf(hp, 0.f), 1.f);
            bn[d] = fminf(fmaxf(hn, 0.f), 1.f);
        }
        // low 2 bits pre-products
        float p00 = bp[0] * bp[1];
        float p10 = bn[0] * bp[1];
        float p01 = bp[0] * bn[1];
        float p11 = bn[0] * bn[1];
        const float4* R4 = (const float4*)(resp + (size_t)t * (U_ * NB_));
        for (int c4 = 0; c4 < 16; c4++) {
            float whi = ((c4 & 1) ? bn[2] : bp[2]) * ((c4 & 2) ? bn[3] : bp[3]) *
                        ((c4 & 4) ? bn[4] : bp[4]) * ((c4 & 8) ? bn[5] : bp[5]);
            float w0 = whi * p00, w1 = whi * p10, w2 = whi * p01, w3 = whi * p11;
#pragma unroll
            for (int u = 0; u < 16; u++) {
                float4 r = R4[u * 16 + c4];
                acc[u] += w0 * r.x + w1 * r.y + w2 * r.z + w3 * r.w;
            }
        }
    }

    // reduce over t_local: xor 8/16/32 within wave, then LDS across 4 waves
#pragma unroll
    for (int u = 0; u < 16; u++) {
        acc[u] += __shfl_xor(acc[u], 8);
        acc[u] += __shfl_xor(acc[u], 16);
        acc[u] += __shfl_xor(acc[u], 32);
    }
    int wave = tid >> 6;
    int lane = tid & 63;
    if (lane < 8) {
#pragma unroll
        for (int u = 0; u < 16; u++) wacc[wave][lane][u] = acc[u];
    }
    __syncthreads();
    if (tid < 128) {
        int b = tid >> 4, u = tid & 15;
        float s = wacc[0][b][u] + wacc[1][b][u] + wacc[2][b][u] + wacc[3][b][u];
        out[(size_t)(b0 + b) * U_ + u] = s;
    }
}

// ---------------------------------------------------------------------------
extern "C" void kernel_launch(void* const* d_in, const int* in_sizes, int n_in,
                              void* d_out, int out_size, void* d_ws, size_t ws_size,
                              hipStream_t stream) {
    const float* x    = (const float*)d_in[0];  // (B,F)
    const float* fsl  = (const float*)d_in[1];  // (F,T,D)
    const float* th   = (const float*)d_in[2];  // (T,D)
    const float* lt   = (const float*)d_in[3];  // (T,D)
    const float* resp = (const float*)d_in[4];  // (T,U,NB)
    float* out = (float*)d_out;                 // (B,U)

    float* sel = (float*)d_ws;                        // F*T*D = 196608 floats
    float* fv  = sel + (size_t)F_ * T_ * D_;          // B*T*D = 3145728 floats

    sparsemax6<<<dim3((F_ * T_ + 255) / 256), dim3(256), 0, stream>>>(fsl, sel, F_ * T_);
    sgemm_fv<<<dim3(N_ / BN, B_ / BM), dim3(256), 0, stream>>>(x, sel, fv);
    leafsum<<<dim3(B_ / 8), dim3(256), 0, stream>>>(fv, th, lt, resp, out);
}

// Round 2
// 103.967 us; speedup vs baseline: 1.6480x; 1.6480x over previous
//
#include <hip/hip_runtime.h>
#include <math.h>

#define B_  4096
#define F_  256
#define T_  128
#define D_  6
#define U_  16
#define NB_ 64
#define N_  (T_ * D_)   // 768

typedef __attribute__((ext_vector_type(8))) short bf16x8;
typedef __attribute__((ext_vector_type(4))) float f32x4;

// fp32 -> bf16 (round-to-nearest-even), bit-exact and branch-free
__device__ __forceinline__ short f2b(float f) {
    union { float f; unsigned u; } v; v.f = f;
    unsigned r = (v.u + 0x7FFFu + ((v.u >> 16) & 1u)) >> 16;
    return (short)r;
}
__device__ __forceinline__ float clamp01(float x) {
    return fminf(fmaxf(x, 0.f), 1.f);
}

// ---------------------------------------------------------------------------
// K1 (fused prep):
//  blocks [0,128):  sparsemax over D=6 rows of (F*T,6); output sel_t bf16
//                   TRANSPOSED to (N_=768, F_=256) = MFMA B-operand layout
//  blocks [128,256): resp fp32 -> bf16 (131072 elems, 4/thread)
//  block 256:       tsc[n] = (exp(-lt), -th*exp(-lt))
// ---------------------------------------------------------------------------
__global__ __launch_bounds__(256) void prep(const float* __restrict__ fsl,
                                            const float* __restrict__ th,
                                            const float* __restrict__ lt,
                                            const float* __restrict__ resp,
                                            unsigned short* __restrict__ sel_t,
                                            unsigned short* __restrict__ resp_b,
                                            float2* __restrict__ tsc) {
    int bid = blockIdx.x, tid = threadIdx.x;
    if (bid < 128) {
        int r = bid * 256 + tid;              // row over (F,T): f = r>>7, t = r&127
        const float* zp = fsl + (size_t)r * 6;
        float v0 = zp[0], v1 = zp[1], v2 = zp[2], v3 = zp[3], v4 = zp[4], v5 = zp[5];
        float s0 = v0, s1 = v1, s2 = v2, s3 = v3, s4 = v4, s5 = v5;
#define CE(a, b) { float hi_ = fmaxf(a, b), lo_ = fminf(a, b); a = hi_; b = lo_; }
        CE(s0, s1) CE(s2, s3) CE(s4, s5)
        CE(s1, s2) CE(s3, s4)
        CE(s0, s1) CE(s2, s3) CE(s4, s5)
        CE(s1, s2) CE(s3, s4)
        CE(s0, s1) CE(s2, s3) CE(s4, s5)
        CE(s1, s2) CE(s3, s4)
#undef CE
        float cum = 0.f, num = 0.f, kz = 1.f;
        cum += s0; num = cum; kz = 1.f;
        cum += s1; if (1.f + 2.f * s1 > cum) { num = cum; kz = 2.f; }
        cum += s2; if (1.f + 3.f * s2 > cum) { num = cum; kz = 3.f; }
        cum += s3; if (1.f + 4.f * s3 > cum) { num = cum; kz = 4.f; }
        cum += s4; if (1.f + 5.f * s4 > cum) { num = cum; kz = 5.f; }
        cum += s5; if (1.f + 6.f * s5 > cum) { num = cum; kz = 6.f; }
        float tau = (num - 1.f) / kz;
        int f = r >> 7, t = r & 127;
        unsigned short* o = sel_t + f;        // column f, rows t*6+d, stride 256
        o[(t * 6 + 0) * 256] = (unsigned short)f2b(fmaxf(v0 - tau, 0.f));
        o[(t * 6 + 1) * 256] = (unsigned short)f2b(fmaxf(v1 - tau, 0.f));
        o[(t * 6 + 2) * 256] = (unsigned short)f2b(fmaxf(v2 - tau, 0.f));
        o[(t * 6 + 3) * 256] = (unsigned short)f2b(fmaxf(v3 - tau, 0.f));
        o[(t * 6 + 4) * 256] = (unsigned short)f2b(fmaxf(v4 - tau, 0.f));
        o[(t * 6 + 5) * 256] = (unsigned short)f2b(fmaxf(v5 - tau, 0.f));
    } else if (bid < 256) {
        int i = (bid - 128) * 256 + tid;      // 32768 threads * 4 elems = 131072
        float4 v = *(const float4*)(resp + (size_t)4 * i);
        ushort4 o;
        o.x = (unsigned short)f2b(v.x); o.y = (unsigned short)f2b(v.y);
        o.z = (unsigned short)f2b(v.z); o.w = (unsigned short)f2b(v.w);
        *(ushort4*)(resp_b + (size_t)4 * i) = o;
    } else {
        for (int i = tid; i < N_; i += 256) {
            float s = expf(-lt[i]);
            tsc[i] = make_float2(s, -th[i] * s);
        }
    }
}

// ---------------------------------------------------------------------------
// K2: fv(4096x768) = x(4096x256) @ sel(256x768) via bf16 MFMA 16x16x32.
// Per-wave 32x32 output tile (2x2 frags), K=256 in 8 steps, no LDS:
//  A-frag: x fp32 loaded 8 floats/lane, converted in-register
//  B-frag: sel_t bf16 (n-major, k contiguous) 16B/lane direct load
// Layouts (verified on gfx950): A[m=lane&15][k=(lane>>4)*8+j];
// B[k=(lane>>4)*8+j][n=lane&15]; D col=lane&15, row=(lane>>4)*4+reg.
// ---------------------------------------------------------------------------
__global__ __launch_bounds__(256) void gemm_fv(const float* __restrict__ x,
                                               const unsigned short* __restrict__ sel_t,
                                               float* __restrict__ fv) {
    int tid = threadIdx.x;
    int lane = tid & 63;
    int wave = tid >> 6;
    int tile = blockIdx.x * 4 + wave;       // 0..3071
    int mT = tile & 127;                    // 128 m-tiles
    int nT = tile >> 7;                     // 24 n-tiles
    int m0 = mT * 32, n0 = nT * 32;
    int lm = lane & 15;
    int kq = lane >> 4;                     // 0..3
    f32x4 acc[2][2] = {};
#pragma unroll
    for (int ks = 0; ks < 8; ks++) {
        int k0 = ks * 32 + kq * 8;
        bf16x8 a[2], b[2];
#pragma unroll
        for (int mt = 0; mt < 2; mt++) {
            const float* ap = x + (size_t)(m0 + mt * 16 + lm) * F_ + k0;
            float4 f0 = *(const float4*)ap;
            float4 f1 = *(const float4*)(ap + 4);
            bf16x8 t;
            t[0] = f2b(f0.x); t[1] = f2b(f0.y); t[2] = f2b(f0.z); t[3] = f2b(f0.w);
            t[4] = f2b(f1.x); t[5] = f2b(f1.y); t[6] = f2b(f1.z); t[7] = f2b(f1.w);
            a[mt] = t;
        }
#pragma unroll
        for (int nt = 0; nt < 2; nt++) {
            const unsigned short* bp = sel_t + (size_t)(n0 + nt * 16 + lm) * F_ + k0;
            b[nt] = *(const bf16x8*)bp;
        }
#pragma unroll
        for (int mt = 0; mt < 2; mt++)
#pragma unroll
            for (int nt = 0; nt < 2; nt++)
                acc[mt][nt] = __builtin_amdgcn_mfma_f32_16x16x32_bf16(a[mt], b[nt], acc[mt][nt], 0, 0, 0);
    }
    int rb = kq * 4;
#pragma unroll
    for (int mt = 0; mt < 2; mt++)
#pragma unroll
        for (int nt = 0; nt < 2; nt++)
#pragma unroll
            for (int r = 0; r < 4; r++)
                fv[(size_t)(m0 + mt * 16 + rb + r) * N_ + n0 + nt * 16 + lm] = acc[mt][nt][r];
}

// ---------------------------------------------------------------------------
// K3: out[b,u] = sum_t W_t(b,:) @ R_t(:,u); per tree two 16x16x32 MFMAs
// (c=0..31, c=32..63) chained into one 16b x 16u accumulator.
// Lane computes its A-fragment w values directly in-layout:
//   c bits 0-2 = j, bits 3-4 = lane>>4, bit 5 = fragment half.
// Block: 512 thr = 8 waves, 16 b-rows; each wave does 16 trees; LDS reduce.
// ---------------------------------------------------------------------------
__global__ __launch_bounds__(512) void leafsum_mfma(const float* __restrict__ fv,
                                                    const unsigned short* __restrict__ resp_b,
                                                    const float2* __restrict__ tsc,
                                                    float* __restrict__ out) {
    __shared__ float red[8][16][17];
    int tid = threadIdx.x;
    int lane = tid & 63;
    int wave = tid >> 6;                   // 0..7
    int b0 = blockIdx.x * 16;
    int lm = lane & 15;                    // A: m (b-row); B: n (u-col)
    int kq = lane >> 4;                    // 0..3
    int q0 = kq & 1, q1 = kq >> 1;         // c bits 3,4
    const float* fvb = fv + (size_t)(b0 + lm) * N_;
    f32x4 acc = {};
    for (int t = wave; t < T_; t += 8) {
        float bp[6], bn[6];
#pragma unroll
        for (int d = 0; d < 6; d++) {
            float2 so = tsc[t * 6 + d];
            float tl = fmaf(fvb[t * 6 + d], so.x, so.y);
            bp[d] = clamp01(fmaf(tl, 0.5f, 0.5f));    // bit=0 factor
            bn[d] = clamp01(fmaf(tl, -0.5f, 0.5f));   // bit=1 factor
        }
        float p01[4] = { bp[0] * bp[1], bn[0] * bp[1], bp[0] * bn[1], bn[0] * bn[1] };
        float p3[8];
#pragma unroll
        for (int j = 0; j < 8; j++) p3[j] = p01[j & 3] * ((j & 4) ? bn[2] : bp[2]);
        float t34 = (q0 ? bn[3] : bp[3]) * (q1 ? bn[4] : bp[4]);
        float w0 = t34 * bp[5], w1 = t34 * bn[5];
        bf16x8 a0, a1;
#pragma unroll
        for (int j = 0; j < 8; j++) {
            a0[j] = f2b(p3[j] * w0);
            a1[j] = f2b(p3[j] * w1);
        }
        const unsigned short* rbp = resp_b + (size_t)t * (U_ * NB_) + lm * NB_ + kq * 8;
        bf16x8 br0 = *(const bf16x8*)rbp;          // c = kq*8+j
        bf16x8 br1 = *(const bf16x8*)(rbp + 32);   // c += 32
        acc = __builtin_amdgcn_mfma_f32_16x16x32_bf16(a0, br0, acc, 0, 0, 0);
        acc = __builtin_amdgcn_mfma_f32_16x16x32_bf16(a1, br1, acc, 0, 0, 0);
    }
#pragma unroll
    for (int r = 0; r < 4; r++) red[wave][kq * 4 + r][lm] = acc[r];
    __syncthreads();
    if (tid < 256) {
        int row = tid >> 4, col = tid & 15;
        float s = 0.f;
#pragma unroll
        for (int w = 0; w < 8; w++) s += red[w][row][col];
        out[(size_t)(b0 + row) * U_ + col] = s;
    }
}

// ---------------------------------------------------------------------------
extern "C" void kernel_launch(void* const* d_in, const int* in_sizes, int n_in,
                              void* d_out, int out_size, void* d_ws, size_t ws_size,
                              hipStream_t stream) {
    const float* x    = (const float*)d_in[0];  // (B,F)
    const float* fsl  = (const float*)d_in[1];  // (F,T,D)
    const float* th   = (const float*)d_in[2];  // (T,D)
    const float* lt   = (const float*)d_in[3];  // (T,D)
    const float* resp = (const float*)d_in[4];  // (T,U,NB)
    float* out = (float*)d_out;                 // (B,U)

    // ws layout (13.24 MB total, under round-0-proven 13.37 MB):
    char* w = (char*)d_ws;
    float*          fv     = (float*)w;                         // 12,582,912 B
    unsigned short* sel_t  = (unsigned short*)(w + 12582912);   //    393,216 B (768x256 bf16)
    unsigned short* resp_b = (unsigned short*)(w + 12976128);   //    262,144 B (128x16x64 bf16)
    float2*         tsc    = (float2*)(w + 13238272);           //      6,144 B

    prep<<<dim3(257), dim3(256), 0, stream>>>(fsl, th, lt, resp, sel_t, resp_b, tsc);
    gemm_fv<<<dim3(768), dim3(256), 0, stream>>>(x, sel_t, fv);
    leafsum_mfma<<<dim3(B_ / 16), dim3(512), 0, stream>>>(fv, resp_b, tsc, out);
}

// Round 3
// 89.401 us; speedup vs baseline: 1.9165x; 1.1629x over previous
//
#include <hip/hip_runtime.h>
#include <math.h>

#define B_  4096
#define F_  256
#define T_  128
#define D_  6
#define U_  16
#define NB_ 64
#define N_  (T_ * D_)   // 768

typedef __attribute__((ext_vector_type(8))) short bf16x8;
typedef __attribute__((ext_vector_type(4))) float f32x4;

// fp32 -> bf16 (round-to-nearest-even)
__device__ __forceinline__ short f2b(float f) {
    union { float f; unsigned u; } v; v.f = f;
    unsigned r = (v.u + 0x7FFFu + ((v.u >> 16) & 1u)) >> 16;
    return (short)r;
}
__device__ __forceinline__ float clamp01(float x) {
    return fminf(fmaxf(x, 0.f), 1.f);
}

// ---------------------------------------------------------------------------
// K1 (prep):
//  blocks [0,128):  sparsemax over D=6 rows of (F*T,6); sel_t bf16 transposed
//                   to (768, 256) = MFMA B-operand layout (n-major, k contig)
//  blocks [128,256): resp fp32 -> bf16
//  block 256:       tsc[n] = (exp(-lt), -th*exp(-lt))
// ---------------------------------------------------------------------------
__global__ __launch_bounds__(256) void prep(const float* __restrict__ fsl,
                                            const float* __restrict__ th,
                                            const float* __restrict__ lt,
                                            const float* __restrict__ resp,
                                            unsigned short* __restrict__ sel_t,
                                            unsigned short* __restrict__ resp_b,
                                            float2* __restrict__ tsc) {
    int bid = blockIdx.x, tid = threadIdx.x;
    if (bid < 128) {
        int r = bid * 256 + tid;              // (f,t): f = r>>7, t = r&127
        const float* zp = fsl + (size_t)r * 6;
        float v0 = zp[0], v1 = zp[1], v2 = zp[2], v3 = zp[3], v4 = zp[4], v5 = zp[5];
        float s0 = v0, s1 = v1, s2 = v2, s3 = v3, s4 = v4, s5 = v5;
#define CE(a, b) { float hi_ = fmaxf(a, b), lo_ = fminf(a, b); a = hi_; b = lo_; }
        CE(s0, s1) CE(s2, s3) CE(s4, s5)
        CE(s1, s2) CE(s3, s4)
        CE(s0, s1) CE(s2, s3) CE(s4, s5)
        CE(s1, s2) CE(s3, s4)
        CE(s0, s1) CE(s2, s3) CE(s4, s5)
        CE(s1, s2) CE(s3, s4)
#undef CE
        float cum = 0.f, num = 0.f, kz = 1.f;
        cum += s0; num = cum; kz = 1.f;
        cum += s1; if (1.f + 2.f * s1 > cum) { num = cum; kz = 2.f; }
        cum += s2; if (1.f + 3.f * s2 > cum) { num = cum; kz = 3.f; }
        cum += s3; if (1.f + 4.f * s3 > cum) { num = cum; kz = 4.f; }
        cum += s4; if (1.f + 5.f * s4 > cum) { num = cum; kz = 5.f; }
        cum += s5; if (1.f + 6.f * s5 > cum) { num = cum; kz = 6.f; }
        float tau = (num - 1.f) / kz;
        int f = r >> 7, t = r & 127;
        unsigned short* o = sel_t + f;        // column f, rows (t*6+d), stride 256
        o[(t * 6 + 0) * 256] = (unsigned short)f2b(fmaxf(v0 - tau, 0.f));
        o[(t * 6 + 1) * 256] = (unsigned short)f2b(fmaxf(v1 - tau, 0.f));
        o[(t * 6 + 2) * 256] = (unsigned short)f2b(fmaxf(v2 - tau, 0.f));
        o[(t * 6 + 3) * 256] = (unsigned short)f2b(fmaxf(v3 - tau, 0.f));
        o[(t * 6 + 4) * 256] = (unsigned short)f2b(fmaxf(v4 - tau, 0.f));
        o[(t * 6 + 5) * 256] = (unsigned short)f2b(fmaxf(v5 - tau, 0.f));
    } else if (bid < 256) {
        int i = (bid - 128) * 256 + tid;      // 32768 threads * 4 = 131072 elems
        float4 v = *(const float4*)(resp + (size_t)4 * i);
        ushort4 o;
        o.x = (unsigned short)f2b(v.x); o.y = (unsigned short)f2b(v.y);
        o.z = (unsigned short)f2b(v.z); o.w = (unsigned short)f2b(v.w);
        *(ushort4*)(resp_b + (size_t)4 * i) = o;
    } else {
        for (int i = tid; i < N_; i += 256) {
            float s = expf(-lt[i]);
            tsc[i] = make_float2(s, -th[i] * s);
        }
    }
}

// ---------------------------------------------------------------------------
// K2 (fused): per block of 16 batch rows:
//   Phase 1: fv_tile(16x768) = x(16x256) @ sel(256x768) via MFMA into LDS.
//     8 waves; wave handles 6 of 48 n-frags (16 cols each), K=256 in 8 steps.
//     A-frag (shared rows, L1-resident): x fp32 -> bf16 in-register.
//     B-frag: sel_t (n-major) direct 16B loads.
//   Phase 2: out[b,u] = sum_t W_t(b,:) @ R_t(:,u); per tree two 16x16x32
//     MFMAs; lane computes the 64 leaf weights directly in A-frag layout
//     (c bits 0-2 = j, 3-4 = lane>>4, 5 = frag half). Wave does 16 trees.
//   fv never touches global memory.
// ---------------------------------------------------------------------------
#define FVP 772   // fv LDS row stride (768+4): phase-2 reads 2-way-conflict max

__global__ __launch_bounds__(512) void fused_gemm_leafsum(
        const float* __restrict__ x,                // (4096,256)
        const unsigned short* __restrict__ sel_t,   // (768,256) bf16
        const unsigned short* __restrict__ resp_b,  // (128,16,64) bf16
        const float2* __restrict__ tsc,             // (768)
        float* __restrict__ out) {                  // (4096,16)
    __shared__ float fvs[16][FVP];                  // 49.4 KB
    __shared__ float red[8][16][17];                //  8.7 KB
    int tid = threadIdx.x;
    int lane = tid & 63;
    int wave = tid >> 6;                   // 0..7
    int b0 = blockIdx.x * 16;
    int lm = lane & 15;
    int kq = lane >> 4;                    // 0..3

    // ---- Phase 1: GEMM into LDS ----
    {
        f32x4 acc[6] = {};
#pragma unroll
        for (int ks = 0; ks < 8; ks++) {
            int k0 = ks * 32 + kq * 8;
            // A-frag: rows b0+lm, k = k0..k0+7 (all waves same -> L1 broadcast)
            const float* ap = x + (size_t)(b0 + lm) * F_ + k0;
            float4 f0 = *(const float4*)ap;
            float4 f1 = *(const float4*)(ap + 4);
            bf16x8 a;
            a[0] = f2b(f0.x); a[1] = f2b(f0.y); a[2] = f2b(f0.z); a[3] = f2b(f0.w);
            a[4] = f2b(f1.x); a[5] = f2b(f1.y); a[6] = f2b(f1.z); a[7] = f2b(f1.w);
#pragma unroll
            for (int i = 0; i < 6; i++) {
                int n = (wave * 6 + i) * 16 + lm;
                bf16x8 b = *(const bf16x8*)(sel_t + (size_t)n * F_ + k0);
                acc[i] = __builtin_amdgcn_mfma_f32_16x16x32_bf16(a, b, acc[i], 0, 0, 0);
            }
        }
#pragma unroll
        for (int i = 0; i < 6; i++) {
            int n0 = (wave * 6 + i) * 16;
#pragma unroll
            for (int r = 0; r < 4; r++)
                fvs[kq * 4 + r][n0 + lm] = acc[i][r];   // D: row=kq*4+r, col=lm
        }
    }
    __syncthreads();

    // ---- Phase 2: leaf weights + response contraction ----
    f32x4 acc = {};
    int q0 = kq & 1, q1 = kq >> 1;         // c bits 3,4
    for (int t = wave; t < T_; t += 8) {
        float bp[6], bn[6];
#pragma unroll
        for (int d = 0; d < 6; d++) {
            float2 so = tsc[t * 6 + d];
            float tl = fmaf(fvs[lm][t * 6 + d], so.x, so.y);
            bp[d] = clamp01(fmaf(tl, 0.5f, 0.5f));     // bit=0 factor
            bn[d] = clamp01(fmaf(tl, -0.5f, 0.5f));    // bit=1 factor
        }
        float p01[4] = { bp[0] * bp[1], bn[0] * bp[1], bp[0] * bn[1], bn[0] * bn[1] };
        float p3[8];
#pragma unroll
        for (int j = 0; j < 8; j++) p3[j] = p01[j & 3] * ((j & 4) ? bn[2] : bp[2]);
        float t34 = (q0 ? bn[3] : bp[3]) * (q1 ? bn[4] : bp[4]);
        float w0 = t34 * bp[5], w1 = t34 * bn[5];
        bf16x8 a0, a1;
#pragma unroll
        for (int j = 0; j < 8; j++) {
            a0[j] = f2b(p3[j] * w0);
            a1[j] = f2b(p3[j] * w1);
        }
        const unsigned short* rbp = resp_b + (size_t)t * (U_ * NB_) + lm * NB_ + kq * 8;
        bf16x8 br0 = *(const bf16x8*)rbp;          // c = kq*8+j
        bf16x8 br1 = *(const bf16x8*)(rbp + 32);   // c += 32
        acc = __builtin_amdgcn_mfma_f32_16x16x32_bf16(a0, br0, acc, 0, 0, 0);
        acc = __builtin_amdgcn_mfma_f32_16x16x32_bf16(a1, br1, acc, 0, 0, 0);
    }
#pragma unroll
    for (int r = 0; r < 4; r++) red[wave][kq * 4 + r][lm] = acc[r];
    __syncthreads();
    if (tid < 256) {
        int row = tid >> 4, col = tid & 15;
        float s = 0.f;
#pragma unroll
        for (int w = 0; w < 8; w++) s += red[w][row][col];
        out[(size_t)(b0 + row) * U_ + col] = s;
    }
}

// ---------------------------------------------------------------------------
extern "C" void kernel_launch(void* const* d_in, const int* in_sizes, int n_in,
                              void* d_out, int out_size, void* d_ws, size_t ws_size,
                              hipStream_t stream) {
    const float* x    = (const float*)d_in[0];  // (B,F)
    const float* fsl  = (const float*)d_in[1];  // (F,T,D)
    const float* th   = (const float*)d_in[2];  // (T,D)
    const float* lt   = (const float*)d_in[3];  // (T,D)
    const float* resp = (const float*)d_in[4];  // (T,U,NB)
    float* out = (float*)d_out;                 // (B,U)

    // ws layout (662 KB; fv eliminated entirely)
    char* w = (char*)d_ws;
    unsigned short* sel_t  = (unsigned short*)w;              // 393,216 B (768x256)
    unsigned short* resp_b = (unsigned short*)(w + 393216);   // 262,144 B
    float2*         tsc    = (float2*)(w + 655360);           //   6,144 B

    prep<<<dim3(257), dim3(256), 0, stream>>>(fsl, th, lt, resp, sel_t, resp_b, tsc);
    fused_gemm_leafsum<<<dim3(B_ / 16), dim3(512), 0, stream>>>(x, sel_t, resp_b, tsc, out);
}

// Round 4
// 87.307 us; speedup vs baseline: 1.9625x; 1.0240x over previous
//
#include <hip/hip_runtime.h>
#include <hip/hip_bf16.h>
#include <math.h>

#define B_  4096
#define F_  256
#define T_  128
#define D_  6
#define U_  16
#define NB_ 64
#define N_  (T_ * D_)   // 768

typedef __attribute__((ext_vector_type(8))) short bf16x8;
typedef __attribute__((ext_vector_type(4))) float f32x4;

// fp32 -> bf16 RNE, scalar (prep only)
__device__ __forceinline__ short f2b(float f) {
    union { float f; unsigned u; } v; v.f = f;
    unsigned r = (v.u + 0x7FFFu + ((v.u >> 16) & 1u)) >> 16;
    return (short)r;
}
// packed pair fp32 -> bf16x2 (v_cvt_pk_bf16_f32 on gfx950); lo -> bits[15:0]
__device__ __forceinline__ unsigned pk2(float lo, float hi) {
    union { __hip_bfloat162 h; unsigned u; } c;
    c.h = __float22bfloat162_rn(make_float2(lo, hi));
    return c.u;
}
__device__ __forceinline__ float clamp01(float x) {
    return fminf(fmaxf(x, 0.f), 1.f);   // v_med3_f32
}

// ---------------------------------------------------------------------------
// K1 (prep):
//  blocks [0,128):  sparsemax over D=6 rows of (F*T,6); sel_t bf16 transposed
//                   to (768,256) = MFMA B-operand layout (n-major, k contig)
//  blocks [128,256): resp fp32 -> bf16
//  block 256:       tsc[n] = (exp(-lt), -th*exp(-lt))
// ---------------------------------------------------------------------------
__global__ __launch_bounds__(256) void prep(const float* __restrict__ fsl,
                                            const float* __restrict__ th,
                                            const float* __restrict__ lt,
                                            const float* __restrict__ resp,
                                            unsigned short* __restrict__ sel_t,
                                            unsigned short* __restrict__ resp_b,
                                            float2* __restrict__ tsc) {
    int bid = blockIdx.x, tid = threadIdx.x;
    if (bid < 128) {
        int r = bid * 256 + tid;              // (f,t): f = r>>7, t = r&127
        const float* zp = fsl + (size_t)r * 6;
        float v0 = zp[0], v1 = zp[1], v2 = zp[2], v3 = zp[3], v4 = zp[4], v5 = zp[5];
        float s0 = v0, s1 = v1, s2 = v2, s3 = v3, s4 = v4, s5 = v5;
#define CE(a, b) { float hi_ = fmaxf(a, b), lo_ = fminf(a, b); a = hi_; b = lo_; }
        CE(s0, s1) CE(s2, s3) CE(s4, s5)
        CE(s1, s2) CE(s3, s4)
        CE(s0, s1) CE(s2, s3) CE(s4, s5)
        CE(s1, s2) CE(s3, s4)
        CE(s0, s1) CE(s2, s3) CE(s4, s5)
        CE(s1, s2) CE(s3, s4)
#undef CE
        float cum = 0.f, num = 0.f, kz = 1.f;
        cum += s0; num = cum; kz = 1.f;
        cum += s1; if (1.f + 2.f * s1 > cum) { num = cum; kz = 2.f; }
        cum += s2; if (1.f + 3.f * s2 > cum) { num = cum; kz = 3.f; }
        cum += s3; if (1.f + 4.f * s3 > cum) { num = cum; kz = 4.f; }
        cum += s4; if (1.f + 5.f * s4 > cum) { num = cum; kz = 5.f; }
        cum += s5; if (1.f + 6.f * s5 > cum) { num = cum; kz = 6.f; }
        float tau = (num - 1.f) / kz;
        int f = r >> 7, t = r & 127;
        unsigned short* o = sel_t + f;        // column f, rows (t*6+d), stride 256
        o[(t * 6 + 0) * 256] = (unsigned short)f2b(fmaxf(v0 - tau, 0.f));
        o[(t * 6 + 1) * 256] = (unsigned short)f2b(fmaxf(v1 - tau, 0.f));
        o[(t * 6 + 2) * 256] = (unsigned short)f2b(fmaxf(v2 - tau, 0.f));
        o[(t * 6 + 3) * 256] = (unsigned short)f2b(fmaxf(v3 - tau, 0.f));
        o[(t * 6 + 4) * 256] = (unsigned short)f2b(fmaxf(v4 - tau, 0.f));
        o[(t * 6 + 5) * 256] = (unsigned short)f2b(fmaxf(v5 - tau, 0.f));
    } else if (bid < 256) {
        int i = (bid - 128) * 256 + tid;      // 32768 threads * 4 = 131072 elems
        float4 v = *(const float4*)(resp + (size_t)4 * i);
        uint2 o;
        o.x = pk2(v.x, v.y);
        o.y = pk2(v.z, v.w);
        *(uint2*)(resp_b + (size_t)4 * i) = o;
    } else {
        for (int i = tid; i < N_; i += 256) {
            float s = expf(-lt[i]);
            tsc[i] = make_float2(s, -th[i] * s);
        }
    }
}

// ---------------------------------------------------------------------------
// K2 (fused), per block of 16 batch rows (grid 256, 512 thr = 8 waves):
//  Phase 1: fv_tile(16x768) = x(16x256) @ sel(256x768) via MFMA into LDS,
//           laid out as fvs[b][t*8+d] (stride-8 per tree, row stride 1028).
//  Phase 1.5: in-place affine: fvs <- fvs*exp(-lt) - th*exp(-lt)  (tl values)
//  Phase 2: per tree: 1x ds_read_b128 + 1x ds_read_b64 gives the 6 tl values;
//           leaf weights built directly in MFMA A-frag layout (c bits 0-2 = j,
//           3-4 = lane>>4, 5 = frag half); two 16x16x32 bf16 MFMAs vs resp.
//  fv never touches global memory.
// ---------------------------------------------------------------------------
#define FVP 1028   // row stride (1024+4): ≡4 mod 32 -> 2-way max aliasing

__global__ __launch_bounds__(512) void fused_gemm_leafsum(
        const float* __restrict__ x,                // (4096,256)
        const unsigned short* __restrict__ sel_t,   // (768,256) bf16
        const unsigned short* __restrict__ resp_b,  // (128,16,64) bf16
        const float2* __restrict__ tsc,             // (768)
        float* __restrict__ out) {                  // (4096,16)
    __shared__ float fvs[16][FVP];                  // 65.8 KB
    __shared__ float red[8][16][17];                //  8.7 KB
    int tid = threadIdx.x;
    int lane = tid & 63;
    int wave = tid >> 6;                   // 0..7
    int b0 = blockIdx.x * 16;
    int lm = lane & 15;
    int kq = lane >> 4;                    // 0..3

    // ---- Phase 1: GEMM into LDS ----
    {
        f32x4 acc[6] = {};
#pragma unroll
        for (int ks = 0; ks < 8; ks++) {
            int k0 = ks * 32 + kq * 8;
            // A-frag: rows b0+lm (all waves identical -> L1 broadcast)
            const float* ap = x + (size_t)(b0 + lm) * F_ + k0;
            float4 f0 = *(const float4*)ap;
            float4 f1 = *(const float4*)(ap + 4);
            union { bf16x8 v; unsigned u[4]; } a;
            a.u[0] = pk2(f0.x, f0.y); a.u[1] = pk2(f0.z, f0.w);
            a.u[2] = pk2(f1.x, f1.y); a.u[3] = pk2(f1.z, f1.w);
#pragma unroll
            for (int i = 0; i < 6; i++) {
                int n = (wave * 6 + i) * 16 + lm;
                bf16x8 b = *(const bf16x8*)(sel_t + (size_t)n * F_ + k0);
                acc[i] = __builtin_amdgcn_mfma_f32_16x16x32_bf16(a.v, b, acc[i], 0, 0, 0);
            }
        }
#pragma unroll
        for (int i = 0; i < 6; i++) {
            int n = (wave * 6 + i) * 16 + lm;   // output col (t,d) = (n/6, n%6)
            int t = n / 6, d = n - t * 6;
            int col = t * 8 + d;
#pragma unroll
            for (int r = 0; r < 4; r++)
                fvs[kq * 4 + r][col] = acc[i][r];   // D: row(b)=kq*4+r, col(n)
        }
    }
    __syncthreads();

    // ---- Phase 1.5: fold thresholds/temperatures in-place ----
    {
        int b = tid & 15;
        int chunk = tid >> 4;              // 0..31, covers n = chunk*24 .. +23
#pragma unroll
        for (int j = 0; j < 24; j++) {
            int n = chunk * 24 + j;
            float2 so = tsc[n];
            int col = (chunk * 4 + j / 6) * 8 + (j % 6);   // t = n/6 compile-time
            fvs[b][col] = fmaf(fvs[b][col], so.x, so.y);
        }
    }
    __syncthreads();

    // ---- Phase 2: leaf weights + response contraction ----
    f32x4 acc = {};
    int q0 = kq & 1, q1 = kq >> 1;         // c bits 3,4
    for (int t = wave; t < T_; t += 8) {
        float4 tl03 = *(const float4*)&fvs[lm][t * 8];       // 16B aligned
        float2 tl45 = *(const float2*)&fvs[lm][t * 8 + 4];
        float tl[6] = { tl03.x, tl03.y, tl03.z, tl03.w, tl45.x, tl45.y };
        float bp[6], bn[6];
#pragma unroll
        for (int d = 0; d < 6; d++) {
            bp[d] = clamp01(fmaf(tl[d],  0.5f, 0.5f));   // bit=0 factor
            bn[d] = clamp01(fmaf(tl[d], -0.5f, 0.5f));   // bit=1 factor
        }
        float p01[4] = { bp[0] * bp[1], bn[0] * bp[1], bp[0] * bn[1], bn[0] * bn[1] };
        float p3[8];
#pragma unroll
        for (int j = 0; j < 8; j++) p3[j] = p01[j & 3] * ((j & 4) ? bn[2] : bp[2]);
        float t34 = (q0 ? bn[3] : bp[3]) * (q1 ? bn[4] : bp[4]);
        float w0 = t34 * bp[5], w1 = t34 * bn[5];
        union { bf16x8 v; unsigned u[4]; } a0, a1;
#pragma unroll
        for (int j = 0; j < 4; j++) {
            a0.u[j] = pk2(p3[2 * j] * w0, p3[2 * j + 1] * w0);
            a1.u[j] = pk2(p3[2 * j] * w1, p3[2 * j + 1] * w1);
        }
        const unsigned short* rbp = resp_b + (size_t)t * (U_ * NB_) + lm * NB_ + kq * 8;
        bf16x8 br0 = *(const bf16x8*)rbp;          // c = kq*8+j
        bf16x8 br1 = *(const bf16x8*)(rbp + 32);   // c += 32
        acc = __builtin_amdgcn_mfma_f32_16x16x32_bf16(a0.v, br0, acc, 0, 0, 0);
        acc = __builtin_amdgcn_mfma_f32_16x16x32_bf16(a1.v, br1, acc, 0, 0, 0);
    }
#pragma unroll
    for (int r = 0; r < 4; r++) red[wave][kq * 4 + r][lm] = acc[r];
    __syncthreads();
    if (tid < 256) {
        int row = tid >> 4, col = tid & 15;
        float s = 0.f;
#pragma unroll
        for (int w = 0; w < 8; w++) s += red[w][row][col];
        out[(size_t)(b0 + row) * U_ + col] = s;
    }
}

// ---------------------------------------------------------------------------
extern "C" void kernel_launch(void* const* d_in, const int* in_sizes, int n_in,
                              void* d_out, int out_size, void* d_ws, size_t ws_size,
                              hipStream_t stream) {
    const float* x    = (const float*)d_in[0];  // (B,F)
    const float* fsl  = (const float*)d_in[1];  // (F,T,D)
    const float* th   = (const float*)d_in[2];  // (T,D)
    const float* lt   = (const float*)d_in[3];  // (T,D)
    const float* resp = (const float*)d_in[4];  // (T,U,NB)
    float* out = (float*)d_out;                 // (B,U)

    // ws layout (662 KB)
    char* w = (char*)d_ws;
    unsigned short* sel_t  = (unsigned short*)w;              // 393,216 B (768x256)
    unsigned short* resp_b = (unsigned short*)(w + 393216);   // 262,144 B
    float2*         tsc    = (float2*)(w + 655360);           //   6,144 B

    prep<<<dim3(257), dim3(256), 0, stream>>>(fsl, th, lt, resp, sel_t, resp_b, tsc);
    fused_gemm_leafsum<<<dim3(B_ / 16), dim3(512), 0, stream>>>(x, sel_t, resp_b, tsc, out);
}